// Round 15
// baseline (227.283 us; speedup 1.0000x reference)
//
#include <hip/hip_runtime.h>

#define BB 32
#define SS 2048
#define VV 516
#define NBS (BB * SS)      // 65536
#define NR 6               // rows per block; 86*6 = 516 exactly
#define NCH 86
#define NPART 256          // comb block count

__device__ __forceinline__ float waveReduceSum(float v) {
    #pragma unroll
    for (int o = 32; o > 0; o >>= 1) v += __shfl_down(v, o, 64);
    return v;
}

// One small block per (b, 6-row slab).  R1-style streaming: ALL loads issued
// at block start (max MLP), exactly two __syncthreads, no in-loop barriers,
// ~11 blocks/CU queued so the CU always has fresh waves issuing loads.
// Per block: read 6 rows (48 KB), exp in registers, 6 parallel wave-reduce
// row sums -> rcp via tiny LDS, per-thread merge of its 6 rows, then per
// s-column one atomicAdd (exp-sum over v) + one atomicMax (packed argmax;
// low word = ~idx so exact-score ties pick the SMALLEST v == np's first-
// index tie-break).  Target logit captured pre-exp (exact) and stored by
// the owning slab.  Cross-slab merge is commutative (max exact; float add
// reorder noise ~1e-6 rel, harness threshold 0.2).
__global__ __launch_bounds__(512, 2) void hl_sweep(const float* __restrict__ x,
                                                   const int* __restrict__ target,
                                                   float* __restrict__ sumAcc,
                                                   unsigned long long* __restrict__ packed,
                                                   float* __restrict__ xtArr) {
    __shared__ float ldsR[8][NR];
    __shared__ float sRcp[NR];

    const int c = blockIdx.x % NCH, b = blockIdx.x / NCH;
    const int v0 = c * NR;
    const int tid = threadIdx.x, lane = tid & 63, wv = tid >> 6;
    const int s0 = tid << 2;
    const int bs = b * SS + s0;

    const float* xb = x + (size_t)(b * VV + v0) * SS + s0;

    // ---- all global loads issued immediately ----
    float4 e0 = *(const float4*)(xb + 0 * (size_t)SS);
    float4 e1 = *(const float4*)(xb + 1 * (size_t)SS);
    float4 e2 = *(const float4*)(xb + 2 * (size_t)SS);
    float4 e3 = *(const float4*)(xb + 3 * (size_t)SS);
    float4 e4 = *(const float4*)(xb + 4 * (size_t)SS);
    float4 e5 = *(const float4*)(xb + 5 * (size_t)SS);
    int4 tg4 = *(const int4*)(target + bs);
    int tg[4] = {tg4.x, tg4.y, tg4.z, tg4.w};

    // ---- capture exact target logits pre-exp ----
    float xt[4] = {0.f, 0.f, 0.f, 0.f};
#define CAPT(EV, R)                                                   \
    { int vg = v0 + (R);                                              \
      if (vg == tg[0]) xt[0] = (EV).x;                                \
      if (vg == tg[1]) xt[1] = (EV).y;                                \
      if (vg == tg[2]) xt[2] = (EV).z;                                \
      if (vg == tg[3]) xt[3] = (EV).w; }
    CAPT(e0, 0) CAPT(e1, 1) CAPT(e2, 2) CAPT(e3, 3) CAPT(e4, 4) CAPT(e5, 5)
#undef CAPT

    // ---- exp in place ----
#define EXP4(EV)                                                      \
    { (EV).x = __expf((EV).x); (EV).y = __expf((EV).y);               \
      (EV).z = __expf((EV).z); (EV).w = __expf((EV).w); }
    EXP4(e0) EXP4(e1) EXP4(e2) EXP4(e3) EXP4(e4) EXP4(e5)
#undef EXP4

    // ---- 6 parallel wave reduces -> row sums ----
    float rp[NR];
    rp[0] = (e0.x + e0.y) + (e0.z + e0.w);
    rp[1] = (e1.x + e1.y) + (e1.z + e1.w);
    rp[2] = (e2.x + e2.y) + (e2.z + e2.w);
    rp[3] = (e3.x + e3.y) + (e3.z + e3.w);
    rp[4] = (e4.x + e4.y) + (e4.z + e4.w);
    rp[5] = (e5.x + e5.y) + (e5.z + e5.w);
    #pragma unroll
    for (int r = 0; r < NR; ++r) rp[r] = waveReduceSum(rp[r]);
    if (lane == 0) {
        #pragma unroll
        for (int r = 0; r < NR; ++r) ldsR[wv][r] = rp[r];
    }
    __syncthreads();
    if (tid < NR) {
        float s = 0.f;
        #pragma unroll
        for (int w = 0; w < 8; ++w) s += ldsR[w][tid];
        sRcp[tid] = 1.f / s;
    }
    __syncthreads();

    // ---- per-thread merge of its 6 rows ----
    float sum[4]  = {0.f, 0.f, 0.f, 0.f};
    float best[4] = {-1.f, -1.f, -1.f, -1.f};
    int   bi[4]   = {v0, v0, v0, v0};
#define ACC(EV, R)                                                    \
    { float rc = sRcp[R]; int vg = v0 + (R);                          \
      sum[0] += (EV).x; sum[1] += (EV).y;                             \
      sum[2] += (EV).z; sum[3] += (EV).w;                             \
      float c0 = (EV).x * rc, c1 = (EV).y * rc,                       \
            c2 = (EV).z * rc, c3 = (EV).w * rc;                       \
      if (c0 > best[0]) { best[0] = c0; bi[0] = vg; }                 \
      if (c1 > best[1]) { best[1] = c1; bi[1] = vg; }                 \
      if (c2 > best[2]) { best[2] = c2; bi[2] = vg; }                 \
      if (c3 > best[3]) { best[3] = c3; bi[3] = vg; } }
    ACC(e0, 0) ACC(e1, 1) ACC(e2, 2) ACC(e3, 3) ACC(e4, 4) ACC(e5, 5)
#undef ACC

    // ---- cross-slab merge: 2 atomics per s-column ----
    #pragma unroll
    for (int i = 0; i < 4; ++i) {
        atomicAdd(sumAcc + bs + i, sum[i]);
        unsigned long long pk =
            ((unsigned long long)__float_as_uint(best[i]) << 32)
          | (unsigned long long)(0xFFFFFFFFu - (unsigned)bi[i]);
        atomicMax(packed + bs + i, pk);
        int lr = tg[i] - v0;
        if (lr >= 0 && lr < NR) xtArr[bs + i] = xt[i];
    }
}

// Finalize per (b,s): nll + penalty mask; block partial sums; last block
// folds the 256 partials into the scalar output.  (R3-proven pattern.)
__global__ __launch_bounds__(256) void hl_comb(const int* __restrict__ target,
                                               const int* __restrict__ ttype,
                                               const float* __restrict__ tval,
                                               const float* __restrict__ coeff,
                                               const float* __restrict__ harm,
                                               const float* __restrict__ sumAcc,
                                               const unsigned long long* __restrict__ packed,
                                               const float* __restrict__ xtArr,
                                               float* __restrict__ pNll,
                                               float* __restrict__ pMask,
                                               int* __restrict__ counter,
                                               float* __restrict__ outv) {
    __shared__ float lds[8];
    __shared__ bool isLast;
    int idx = blockIdx.x * 256 + threadIdx.x;            // (b,s) flat

    unsigned long long pk = packed[idx];
    int bestIdx = (int)(0xFFFFFFFFu - (unsigned)(pk & 0xFFFFFFFFull));
    float nll = __logf(sumAcc[idx]) - xtArr[idx];
    int tgt = target[idx];

    int pt = ttype[bestIdx], tt = ttype[tgt];
    float pv = tval[bestIdx], tv = tval[tgt];
    float d = fabsf(pv - tv);
    float pw = (d == 7.f) ? harm[0] : (d == 5.f) ? harm[1] : (d == 3.f) ? harm[2]
             : (d == 4.f) ? harm[3] : (d == 1.f) ? harm[4] : (d == 2.f) ? harm[5]
             : harm[6];
    float w = (pt == 0) ? pw
            : (pt == 1) ? coeff[1] * d * (1.f / 160.f)
            : (pt == 2) ? coeff[2] * d * (1.f / 100.f)
            :             coeff[3] * d * (1.f / 128.f);
    float mask = (pt != tt) ? coeff[0] : w;

    int lane = threadIdx.x & 63, wvv = threadIdx.x >> 6;
    float rn = waveReduceSum(nll);
    if (lane == 0) lds[wvv] = rn;
    __syncthreads();
    float totN = (threadIdx.x == 0) ? lds[0] + lds[1] + lds[2] + lds[3] : 0.f;
    __syncthreads();
    float rm = waveReduceSum(mask);
    if (lane == 0) lds[wvv] = rm;
    __syncthreads();
    if (threadIdx.x == 0) {
        pNll[blockIdx.x]  = totN;
        pMask[blockIdx.x] = lds[0] + lds[1] + lds[2] + lds[3];
        __threadfence();
        unsigned old = atomicAdd((unsigned*)counter, 1u);
        isLast = (old == NPART - 1);
    }
    __syncthreads();
    if (isLast) {
        __threadfence();
        int t = threadIdx.x;
        float n = waveReduceSum(pNll[t]);
        float m = waveReduceSum(pMask[t]);
        if (lane == 0) { lds[wvv] = n; lds[4 + wvv] = m; }
        __syncthreads();
        if (t == 0) {
            float tn = lds[0] + lds[1] + lds[2] + lds[3];
            float tm = lds[4] + lds[5] + lds[6] + lds[7];
            const float inv = 1.f / (float)NBS;
            outv[0] = (tn * inv) * (1.f + tm * inv);
        }
    }
}

extern "C" void kernel_launch(void* const* d_in, const int* in_sizes, int n_in,
                              void* d_out, int out_size, void* d_ws, size_t ws_size,
                              hipStream_t stream) {
    const float* x      = (const float*)d_in[0];
    const int*   target = (const int*)d_in[1];
    const int*   ttype  = (const int*)d_in[2];
    const float* tval   = (const float*)d_in[3];
    const float* coeff  = (const float*)d_in[4];
    const float* harm   = (const float*)d_in[5];

    float* ws = (float*)d_ws;
    int*                ctr    = (int*)ws;                         // 16 B
    float*              sumAcc = ws + 4;                           // 256 KB
    unsigned long long* packed = (unsigned long long*)(sumAcc + NBS); // 512 KB (8B-aligned: 16+262144)
    float*              xtArr  = (float*)(packed + NBS);           // 256 KB
    float*              pNll   = xtArr + NBS;                      // 1 KB
    float*              pMask  = pNll + NPART;                     // 1 KB

    // zero ctr + sumAcc + packed (contiguous prefix of ws)
    hipMemsetAsync(d_ws, 0, 16 + (size_t)NBS * 4 + (size_t)NBS * 8, stream);

    hl_sweep<<<BB * NCH, 512, 0, stream>>>(x, target, sumAcc, packed, xtArr);
    hl_comb<<<NBS / 256, 256, 0, stream>>>(target, ttype, tval, coeff, harm,
                                           sumAcc, packed, xtArr,
                                           pNll, pMask, ctr, (float*)d_out);
}